// Round 16
// baseline (190.476 us; speedup 1.0000x reference)
//
#include <hip/hip_runtime.h>
#include <hip/hip_bf16.h>

// B=4, T=1024, E=1024, ATT=64, NH=16, AH=1024. M = B*T = 4096, K = N = 1024.
// Pipeline: cast x->bf16; transpose+cast W{q,k,v,o} -> [N][K] bf16;
//           fused QKV MFMA GEMM (128x128, BK=64 slab-pair, global_load_lds,
//           XCD-chunked swizzle, HEAD-MAJOR Q/K/V epilogue, K pre-scaled by
//           0.125*log2e); register-path MFMA flash attention (S^T trick,
//           HW v_exp_f32, key-split 8-wave); split-K 8-wave O-proj GEMM.
//
// ROUND 16 = ROUND 15 RESUBMITTED UNCHANGED (r15 was an infra failure:
// "MI355X container failed twice", kernel never executed; code re-audited
// for crash-capable defects — none found).
// ROUND 15 RATIONALE: O-proj was the hidden hog (~50us at ~170 TF): 512
// blocks x 256 thr = 2 blocks/CU = 8 waves/CU (2/SIMD) — too little TLP
// to cover the per-K-step barrier drains. New gemm_oproj: 512 thr = 8
// waves; waves 0-3 own K[0,512), waves 4-7 own K[512,1024) (r8 attn
// key-split pattern applied to GEMM): per-wave barrier count halves,
// waves/CU doubles to 16, MFMA:barrier ratio unchanged. Partials combine
// additively via LDS (reusing dead staging space); grp 0 adds bias,
// stores fp32.

typedef __bf16 bf16_t;
typedef bf16_t bf16x8 __attribute__((ext_vector_type(8)));
typedef bf16_t bf16x4 __attribute__((ext_vector_type(4)));
typedef short  s16x4 __attribute__((ext_vector_type(4)));
typedef float  f32x4 __attribute__((ext_vector_type(4)));

#define SCALE_LOG2E 0.18033688011112042f  /* 0.125 * log2(e) */

__device__ __forceinline__ void async16(const bf16_t* g, void* l) {
    __builtin_amdgcn_global_load_lds(
        (const __attribute__((address_space(1))) unsigned int*)g,
        (__attribute__((address_space(3))) unsigned int*)l,
        16, 0, 0);
}

// ---------- cast fp32 -> bf16, 8 elems/thread ----------
__global__ __launch_bounds__(256) void cast_f32_bf16(
    const float* __restrict__ in, bf16_t* __restrict__ out, int n8)
{
    int i = blockIdx.x * 256 + threadIdx.x;
    if (i >= n8) return;
    const float4* p = (const float4*)in + (size_t)i * 2;
    float4 a = p[0], b = p[1];
    bf16x8 o;
    o[0] = (bf16_t)a.x; o[1] = (bf16_t)a.y; o[2] = (bf16_t)a.z; o[3] = (bf16_t)a.w;
    o[4] = (bf16_t)b.x; o[5] = (bf16_t)b.y; o[6] = (bf16_t)b.z; o[7] = (bf16_t)b.w;
    *((bf16x8*)out + i) = o;
}

// ---------- transpose + cast: W [1024][1024] fp32 [K][N] -> [N][K] bf16 ----------
__global__ __launch_bounds__(256) void transpose_cast(
    const float* __restrict__ W0, const float* __restrict__ W1,
    const float* __restrict__ W2, const float* __restrict__ W3,
    bf16_t* __restrict__ out)
{
    __shared__ float st[32][33];
    const float* W = (blockIdx.z == 0) ? W0 : (blockIdx.z == 1) ? W1
                   : (blockIdx.z == 2) ? W2 : W3;
    bf16_t* o = out + (size_t)blockIdx.z * 1024 * 1024;
    const int n0 = blockIdx.x * 32, k0 = blockIdx.y * 32;
    const int t = threadIdx.x;
    const int r = t >> 3, c4 = (t & 7) * 4;
    float4 v = *(const float4*)(W + (size_t)(k0 + r) * 1024 + n0 + c4);
    st[r][c4 + 0] = v.x; st[r][c4 + 1] = v.y; st[r][c4 + 2] = v.z; st[r][c4 + 3] = v.w;
    __syncthreads();
    bf16_t tmp[4] __attribute__((aligned(8)));
    #pragma unroll
    for (int i = 0; i < 4; ++i) tmp[i] = (bf16_t)st[c4 + i][r];
    *(uint2*)(o + (size_t)(n0 + r) * 1024 + k0 + c4) = *(const uint2*)tmp;
}

// ---------- fused QKV MFMA GEMM (UNCHANGED from r14) ----------
// 128x128 tile, BK=64 slab-pair, XCD-chunked swizzle, head-major epilogue.
template<bool FUSED, int MT>
__global__ __launch_bounds__(256, 3) void gemm_glds(
    const bf16_t* __restrict__ A, const bf16_t* __restrict__ Bt,
    const float* __restrict__ b0, const float* __restrict__ b1,
    const float* __restrict__ b2,
    bf16_t* __restrict__ Qo, bf16_t* __restrict__ Ko, bf16_t* __restrict__ Vo,
    float* __restrict__ Fo)
{
    const int K = 1024;
    __shared__ __align__(16) bf16_t As[2 * MT * 32];
    __shared__ __align__(16) bf16_t Bs[2 * 128 * 32];

    constexpr int NTPW = (MT == 128) ? 4 : 2;
    constexpr int JA   = MT / 64;
    constexpr int NX   = FUSED ? 24 : 8;            // grid.x
    constexpr int NWG  = NX * ((MT == 128) ? 32 : 64);

    const int tid  = threadIdx.x;
    const int wave = tid >> 6;
    const int lane = tid & 63;
    const int quad = lane >> 4;
    const int l16  = lane & 15;

    int flat = blockIdx.y * NX + blockIdx.x;
    flat = (flat & 7) * (NWG >> 3) + (flat >> 3);
    const int m0 = (flat / NX) * MT;
    const int n0 = (flat % NX) * 128;

    const int wm = (MT == 128) ? (wave >> 1) * 64 : 0;
    const int wn = (MT == 128) ? (wave & 1) * 64 : wave * 32;

    int goffA[JA], goffB[2];
    #pragma unroll
    for (int j = 0; j < JA; ++j) {
        const int row = j * 64 + (tid >> 2);
        const int cl  = (tid & 3) ^ ((row >> 1) & 3);
        goffA[j] = (m0 + row) * K + cl * 8;
    }
    #pragma unroll
    for (int j = 0; j < 2; ++j) {
        const int row = j * 64 + (tid >> 2);
        const int cl  = (tid & 3) ^ ((row >> 1) & 3);
        goffB[j] = (n0 + row) * K + cl * 8;
    }
    const int ldsoff = wave * 1024;

    f32x4 acc[4][NTPW] = {};
    const int sw = (l16 >> 1) & 3;

    for (int k0 = 0; k0 < K; k0 += 64) {
        #pragma unroll
        for (int s = 0; s < 2; ++s) {
            #pragma unroll
            for (int j = 0; j < JA; ++j)
                async16(A + goffA[j] + k0 + s * 32,
                        (char*)As + s * (MT * 64) + j * 4096 + ldsoff);
            #pragma unroll
            for (int j = 0; j < 2; ++j)
                async16(Bt + goffB[j] + k0 + s * 32,
                        (char*)Bs + s * 8192 + j * 4096 + ldsoff);
        }
        __syncthreads();

        #pragma unroll
        for (int s = 0; s < 2; ++s) {
            bf16x8 af[4], bfr[NTPW];
            #pragma unroll
            for (int mt = 0; mt < 4; ++mt)
                af[mt] = *(const bf16x8*)(&As[s * (MT * 32) +
                    (wm + mt * 16 + l16) * 32 + (quad ^ sw) * 8]);
            #pragma unroll
            for (int nt = 0; nt < NTPW; ++nt)
                bfr[nt] = *(const bf16x8*)(&Bs[s * (128 * 32) +
                    (wn + nt * 16 + l16) * 32 + (quad ^ sw) * 8]);
            #pragma unroll
            for (int mt = 0; mt < 4; ++mt)
                #pragma unroll
                for (int nt = 0; nt < NTPW; ++nt)
                    acc[mt][nt] = __builtin_amdgcn_mfma_f32_16x16x32_bf16(
                        af[mt], bfr[nt], acc[mt][nt], 0, 0, 0);
        }
        __syncthreads();
    }

    if (FUSED) {
        const int sel = n0 >> 10;
        const float* bias = (sel == 0) ? b0 : (sel == 1) ? b1 : b2;
        bf16_t* Cout      = (sel == 0) ? Qo : (sel == 1) ? Ko : Vo;
        const float scl   = (sel == 1) ? SCALE_LOG2E : 1.0f;
        const int nb = n0 & 1023;
        #pragma unroll
        for (int nt = 0; nt < NTPW; ++nt) {
            const int n = nb + wn + nt * 16 + l16;
            const float bb = bias[n];
            const size_t hbase = (size_t)(n >> 4) * 65536 + (n & 15);
            #pragma unroll
            for (int mt = 0; mt < 4; ++mt)
                #pragma unroll
                for (int i = 0; i < 4; ++i) {
                    const int m = m0 + wm + mt * 16 + quad * 4 + i;
                    Cout[hbase + (size_t)m * 16] = (bf16_t)((acc[mt][nt][i] + bb) * scl);
                }
        }
    } else {
        #pragma unroll
        for (int nt = 0; nt < NTPW; ++nt) {
            const int n = n0 + wn + nt * 16 + l16;
            const float bb = b0[n];
            #pragma unroll
            for (int mt = 0; mt < 4; ++mt)
                #pragma unroll
                for (int i = 0; i < 4; ++i) {
                    const int m = m0 + wm + mt * 16 + quad * 4 + i;
                    Fo[(size_t)m * 1024 + n] = acc[mt][nt][i] + bb;
                }
        }
    }
}

// ---------- split-K O-proj GEMM: out = Z[4096,1024] @ WtO^T + bo ----------
// 512 thr = 8 waves. Waves 0-3 (grp 0): 64x128 tile over K[0,512);
// waves 4-7 (grp 1): same tile over K[512,1024). Each group has its own
// LDS staging (48KB total); grid 512 -> 2 blocks/CU = 16 waves/CU, 2x the
// old O-proj. Per-wave loop is 8 BK=64 slab-pair iters (was 16). Combine:
// grp 1 writes acc to LDS (reuses dead staging), grp 0 adds + bias + store.
__global__ __launch_bounds__(512, 4) void gemm_oproj(
    const bf16_t* __restrict__ A, const bf16_t* __restrict__ Bt,
    const float* __restrict__ bias, float* __restrict__ Fo)
{
    __shared__ __align__(16) char smem[49152];
    bf16_t* As  = (bf16_t*)smem;               // [grp][2 slabs][64*32] 16KB
    bf16_t* Bs  = (bf16_t*)(smem + 16384);     // [grp][2 slabs][128*32] 32KB
    float*  cmb = (float*)smem;                // combine: 256 lanes x 32 f32

    const int K = 1024;
    const int tid  = threadIdx.x;
    const int wave = tid >> 6;      // 0..7
    const int grp  = wave >> 2;     // K-half
    const int qw   = wave & 3;
    const int lane = tid & 63;
    const int quad = lane >> 4;
    const int l16  = lane & 15;
    const int tl   = tid & 255;     // within-group thread id

    int flat = blockIdx.y * 8 + blockIdx.x;    // grid (8, 64) = 512
    flat = (flat & 7) * 64 + (flat >> 3);      // XCD chunk (512 % 8 == 0)
    const int m0 = (flat >> 3) * 64;
    const int n0 = (flat & 7) * 128;
    const int wn = qw * 32;
    const int kb = grp * 512;

    const int rowA  = tl >> 2;
    const int clA   = (tl & 3) ^ ((rowA >> 1) & 3);
    const int goffA = (m0 + rowA) * K + kb + clA * 8;
    int goffB[2];
    #pragma unroll
    for (int j = 0; j < 2; ++j) {
        const int row = j * 64 + (tl >> 2);
        const int cl  = (tl & 3) ^ ((row >> 1) & 3);
        goffB[j] = (n0 + row) * K + kb + cl * 8;
    }
    const int ldsoffq = qw * 1024;   // within-group wave byte offset

    f32x4 acc[4][2] = {};
    const int sw = (l16 >> 1) & 3;

    for (int k0 = 0; k0 < 512; k0 += 64) {
        #pragma unroll
        for (int s = 0; s < 2; ++s) {
            async16(A + goffA + k0 + s * 32,
                    (char*)As + grp * 8192 + s * 4096 + ldsoffq);
            #pragma unroll
            for (int j = 0; j < 2; ++j)
                async16(Bt + goffB[j] + k0 + s * 32,
                        (char*)Bs + grp * 16384 + s * 8192 + j * 4096 + ldsoffq);
        }
        __syncthreads();

        #pragma unroll
        for (int s = 0; s < 2; ++s) {
            bf16x8 af[4], bfr[2];
            #pragma unroll
            for (int mt = 0; mt < 4; ++mt)
                af[mt] = *(const bf16x8*)(&As[grp * 4096 + s * 2048 +
                    (mt * 16 + l16) * 32 + (quad ^ sw) * 8]);
            #pragma unroll
            for (int nt = 0; nt < 2; ++nt)
                bfr[nt] = *(const bf16x8*)(&Bs[grp * 8192 + s * 4096 +
                    (wn + nt * 16 + l16) * 32 + (quad ^ sw) * 8]);
            #pragma unroll
            for (int mt = 0; mt < 4; ++mt)
                #pragma unroll
                for (int nt = 0; nt < 2; ++nt)
                    acc[mt][nt] = __builtin_amdgcn_mfma_f32_16x16x32_bf16(
                        af[mt], bfr[nt], acc[mt][nt], 0, 0, 0);
        }
        __syncthreads();
    }

    // combine halves (staging LDS is dead now; loop's trailing barrier done)
    if (grp == 1) {
        float* p = cmb + ((size_t)(qw * 64 + lane)) * 32;
        #pragma unroll
        for (int mt = 0; mt < 4; ++mt)
            #pragma unroll
            for (int nt = 0; nt < 2; ++nt)
                #pragma unroll
                for (int i = 0; i < 4; ++i)
                    p[mt * 8 + nt * 4 + i] = acc[mt][nt][i];
    }
    __syncthreads();
    if (grp == 0) {
        const float* p = cmb + ((size_t)(qw * 64 + lane)) * 32;
        #pragma unroll
        for (int nt = 0; nt < 2; ++nt) {
            const int n = n0 + wn + nt * 16 + l16;
            const float bb = bias[n];
            #pragma unroll
            for (int mt = 0; mt < 4; ++mt)
                #pragma unroll
                for (int i = 0; i < 4; ++i) {
                    const int m = m0 + mt * 16 + quad * 4 + i;
                    Fo[(size_t)m * 1024 + n] =
                        acc[mt][nt][i] + p[mt * 8 + nt * 4 + i] + bb;
                }
        }
    }
}

// ---------- MFMA flash attention, key-split 8-wave, head-major inputs ----------
// UNCHANGED from r14 (52.8us). PARKED: 6 structural levers each moved <=2us;
// latency-bound with issue slack (r11 pack-width null).
// LEDGER: r10 inline-asm cvt_pk after v_exp => NaN — never hand-write.
__global__ __launch_bounds__(512, 4) void attn_kernel(
    const bf16_t* __restrict__ Q, const bf16_t* __restrict__ K,
    const bf16_t* __restrict__ V, bf16_t* __restrict__ Z)
{
    __shared__ __align__(16) char smem[16 * 1032 * 2];
    bf16_t (*Vt)[1032] = (bf16_t (*)[1032])smem;
    float* cmb = (float*)smem;     // [4 waves][64 lanes][21]

    const int tid  = threadIdx.x;
    const int wave = tid >> 6;        // 0..7
    const int lane = tid & 63;
    const int quad = lane >> 4;
    const int l16  = lane & 15;
    const int hd = blockIdx.x >> 2;
    const int qc = blockIdx.x & 3;
    const int a = hd >> 2, b = hd & 3;
    const int qw   = wave & 3;
    const int kvh  = wave >> 2;
    const int qbase = qc * 256 + qw * 64;
    const int kb512 = kvh * 512;

    const size_t hb = (size_t)a * 65536 + (size_t)b * 1024 * 16;

    const int r  = tid >> 2;
    const int dq = (tid & 3) * 4;
    const bf16_t* Vp = V + hb + (size_t)r * 16 + dq;
    #pragma unroll 2
    for (int t = 0; t < 8; ++t) {
        uint2 vv = *(const uint2*)(Vp + t * 2048);   // +128 rows
        bf16_t t4[4] __attribute__((aligned(8)));
        *(uint2*)t4 = vv;
        #pragma unroll
        for (int ii = 0; ii < 4; ++ii)
            Vt[dq + ii][t * 128 + r] = t4[ii];
    }

    bf16x8 qf[4] = {};
    if (quad < 2) {
        #pragma unroll
        for (int qs = 0; qs < 4; ++qs)
            qf[qs] = *(const bf16x8*)(Q + hb +
                (size_t)(qbase + qs * 16 + l16) * 16 + quad * 8);
    }

    const bf16_t* Kp = K + hb + (size_t)(kb512 + l16) * 16 + quad * 8;
    bf16x8 kfA[4] = {}, kfB[4] = {};
    if (quad < 2) {
        #pragma unroll
        for (int kt = 0; kt < 4; ++kt)
            kfA[kt] = *(const bf16x8*)(Kp + kt * 256);   // +16 rows
    }

    __syncthreads();   // Vt ready

    const s16x4 ones = { 0x3F80, 0x3F80, 0x3F80, 0x3F80 };  // bf16 1.0 x4

    f32x4 zacc[4] = {};
    f32x4 lacc[4] = {};

#define ATTN_TILE(JIDX, KFCUR, KFNXT, DO_PREFETCH)                            \
    {                                                                         \
        const int j_ = (JIDX);                                                \
        if (DO_PREFETCH && quad < 2) {                                        \
            _Pragma("unroll")                                                 \
            for (int kt = 0; kt < 4; ++kt)                                    \
                KFNXT[kt] = *(const bf16x8*)(                                 \
                    Kp + (j_ + 1) * 1024 + kt * 256);                         \
        }                                                                     \
        _Pragma("unroll")                                                     \
        for (int kt = 0; kt < 4; ++kt) {                                      \
            const s16x4 vfrag = __builtin_bit_cast(s16x4,                     \
                *(const uint2*)(&Vt[l16][kb512 + j_ * 64 + kt * 16 + quad * 4])); \
            _Pragma("unroll")                                                 \
            for (int qs = 0; qs < 4; ++qs) {                                  \
                f32x4 zc = {0.f, 0.f, 0.f, 0.f};                              \
                f32x4 s = __builtin_amdgcn_mfma_f32_16x16x32_bf16(            \
                    KFCUR[kt], qf[qs], zc, 0, 0, 0);                          \
                const float e0 = __builtin_amdgcn_exp2f(s[0]);                \
                const float e1 = __builtin_amdgcn_exp2f(s[1]);                \
                const float e2 = __builtin_amdgcn_exp2f(s[2]);                \
                const float e3 = __builtin_amdgcn_exp2f(s[3]);                \
                bf16x4 pv;                                                    \
                pv[0] = (bf16_t)e0; pv[1] = (bf16_t)e1;                       \
                pv[2] = (bf16_t)e2; pv[3] = (bf16_t)e3;                       \
                const s16x4 pfrag = __builtin_bit_cast(s16x4, pv);            \
                zacc[qs] = __builtin_amdgcn_mfma_f32_16x16x16bf16_1k(         \
                    vfrag, pfrag, zacc[qs], 0, 0, 0);                         \
                lacc[qs] = __builtin_amdgcn_mfma_f32_16x16x16bf16_1k(         \
                    ones, pfrag, lacc[qs], 0, 0, 0);                          \
            }                                                                 \
        }                                                                     \
    }

    #pragma unroll 1
    for (int j2 = 0; j2 < 4; ++j2) {
        ATTN_TILE(2 * j2,     kfA, kfB, true)
        ATTN_TILE(2 * j2 + 1, kfB, kfA, (j2 < 3))
    }
#undef ATTN_TILE

    __syncthreads();
    if (wave >= 4) {
        float* p = cmb + ((size_t)((wave - 4) * 64 + lane)) * 21;
        #pragma unroll
        for (int qs = 0; qs < 4; ++qs) {
            #pragma unroll
            for (int i = 0; i < 4; ++i) p[qs * 4 + i] = zacc[qs][i];
            p[16 + qs] = lacc[qs][0];
        }
    }
    __syncthreads();
    if (wave < 4) {
        const float* p = cmb + ((size_t)(wave * 64 + lane)) * 21;
        #pragma unroll
        for (int qs = 0; qs < 4; ++qs) {
            const float inv = 1.0f / (lacc[qs][0] + p[16 + qs]);
            const int q = qbase + qs * 16 + l16;
            bf16_t o4[4] __attribute__((aligned(8)));
            #pragma unroll
            for (int i = 0; i < 4; ++i)
                o4[i] = (bf16_t)((zacc[qs][i] + p[qs * 4 + i]) * inv);
            *(uint2*)(Z + ((size_t)hd * 1024 + q) * 16 + quad * 4) = *(const uint2*)o4;
        }
    }
}

extern "C" void kernel_launch(void* const* d_in, const int* in_sizes, int n_in,
                              void* d_out, int out_size, void* d_ws, size_t ws_size,
                              hipStream_t stream) {
    const float* x  = (const float*)d_in[0];
    const float* Wq = (const float*)d_in[1];
    const float* bq = (const float*)d_in[2];
    const float* Wk = (const float*)d_in[3];
    const float* bk = (const float*)d_in[4];
    const float* Wv = (const float*)d_in[5];
    const float* bv = (const float*)d_in[6];
    const float* Wo = (const float*)d_in[7];
    const float* bo = (const float*)d_in[8];
    float* out = (float*)d_out;

    char* ws = (char*)d_ws;
    bf16_t* x_bf = (bf16_t*)(ws);
    bf16_t* Wt   = (bf16_t*)(ws + (8u << 20));   // q|k|v|o slabs, contiguous
    bf16_t* Qb   = (bf16_t*)(ws + (16u << 20));
    bf16_t* Kb   = (bf16_t*)(ws + (24u << 20));
    bf16_t* Vb   = (bf16_t*)(ws + (32u << 20));
    bf16_t* Zb   = (bf16_t*)(ws + (40u << 20));
    bf16_t* WtO  = Wt + (size_t)3 * 1024 * 1024;

    cast_f32_bf16<<<dim3(2048), dim3(256), 0, stream>>>(x, x_bf, 524288);
    transpose_cast<<<dim3(32, 32, 4), dim3(256), 0, stream>>>(Wq, Wk, Wv, Wo, Wt);

    // fused QKV: Bt = [3072][1024] (Wq|Wk|Wv); Q/K/V written head-major
    gemm_glds<true, 128><<<dim3(24, 32), dim3(256), 0, stream>>>(
        x_bf, Wt, bq, bk, bv, Qb, Kb, Vb, nullptr);

    attn_kernel<<<dim3(1024), dim3(512), 0, stream>>>(Qb, Kb, Vb, Zb);

    // O-projection: split-K 8-wave, 512 blocks x 512 thr (16 waves/CU)
    gemm_oproj<<<dim3(8, 64), dim3(512), 0, stream>>>(Zb, WtO, bo, out);
}

// Round 17
// 184.730 us; speedup vs baseline: 1.0311x; 1.0311x over previous
//
#include <hip/hip_runtime.h>
#include <hip/hip_bf16.h>

// B=4, T=1024, E=1024, ATT=64, NH=16, AH=1024. M = B*T = 4096, K = N = 1024.
// Pipeline: merged prologue (cast x->bf16 + transpose/cast W -> [N][K] bf16);
//           fused QKV MFMA GEMM (128x128, BK=64 slab-pair, global_load_lds,
//           XCD-chunked swizzle, HEAD-MAJOR Q/K/V epilogue, K pre-scaled by
//           0.125*log2e); register-path MFMA flash attention (S^T trick,
//           HW v_exp_f32, key-split 8-wave); O-proj GEMM (r14 form).
//
// ROUND 17: (1) REVERT split-K O-proj (r15/16): neutral-to-negative —
// 16-wave barriers + combine overhead ate the TLP gain (r16: 190.5 on a
// slow node; attn-normalized ~184 > r14's 180.7). Back to r14's
// gemm_glds<false,64> 512-block O-proj. (2) ONE CHANGE: merge the two
// prologue kernels into one launch (grid z=0..3: W transpose, z=4: x cast)
// — both BW-bound and independent; removes a launch gap and overlaps the
// cast with the transpose tail. Zero numerics change.
// LEDGER: r10 inline-asm cvt_pk after v_exp => NaN — never hand-write.
// r12 explicit GEMM dbuf +9us (TLP already covers drain). r13 XCD swizzle
// null (L3 absorbs) — kept, harmless. r14 head-major QKV −6us (best:
// 180.7). r15/16 split-K O-proj: reverted.

typedef __bf16 bf16_t;
typedef bf16_t bf16x8 __attribute__((ext_vector_type(8)));
typedef bf16_t bf16x4 __attribute__((ext_vector_type(4)));
typedef short  s16x4 __attribute__((ext_vector_type(4)));
typedef float  f32x4 __attribute__((ext_vector_type(4)));

#define SCALE_LOG2E 0.18033688011112042f  /* 0.125 * log2(e) */

__device__ __forceinline__ void async16(const bf16_t* g, void* l) {
    __builtin_amdgcn_global_load_lds(
        (const __attribute__((address_space(1))) unsigned int*)g,
        (__attribute__((address_space(3))) unsigned int*)l,
        16, 0, 0);
}

// ---------- merged prologue: z<4 -> transpose+cast W[z]; z==4 -> cast x ----------
// Transpose path identical to the proven transpose_cast (32x32 LDS tile,
// +1-pad). Cast path: 1024 blocks x 256 thr x 16 elems = 4M elems of x.
__global__ __launch_bounds__(256) void prologue(
    const float* __restrict__ x,
    const float* __restrict__ W0, const float* __restrict__ W1,
    const float* __restrict__ W2, const float* __restrict__ W3,
    bf16_t* __restrict__ x_bf, bf16_t* __restrict__ Wt)
{
    __shared__ float st[32][33];
    const int t = threadIdx.x;

    if (blockIdx.z == 4) {
        // cast x -> bf16, 16 elems/thread
        const int i = (blockIdx.y * 32 + blockIdx.x) * 256 + t;   // 0..262143
        const float4* p = (const float4*)x + (size_t)i * 4;
        float4 a = p[0], b = p[1], c = p[2], d = p[3];
        bf16x8 o0, o1;
        o0[0] = (bf16_t)a.x; o0[1] = (bf16_t)a.y; o0[2] = (bf16_t)a.z; o0[3] = (bf16_t)a.w;
        o0[4] = (bf16_t)b.x; o0[5] = (bf16_t)b.y; o0[6] = (bf16_t)b.z; o0[7] = (bf16_t)b.w;
        o1[0] = (bf16_t)c.x; o1[1] = (bf16_t)c.y; o1[2] = (bf16_t)c.z; o1[3] = (bf16_t)c.w;
        o1[4] = (bf16_t)d.x; o1[5] = (bf16_t)d.y; o1[6] = (bf16_t)d.z; o1[7] = (bf16_t)d.w;
        *((bf16x8*)x_bf + (size_t)i * 2)     = o0;
        *((bf16x8*)x_bf + (size_t)i * 2 + 1) = o1;
        return;
    }

    const float* W = (blockIdx.z == 0) ? W0 : (blockIdx.z == 1) ? W1
                   : (blockIdx.z == 2) ? W2 : W3;
    bf16_t* o = Wt + (size_t)blockIdx.z * 1024 * 1024;
    const int n0 = blockIdx.x * 32, k0 = blockIdx.y * 32;
    const int r = t >> 3, c4 = (t & 7) * 4;
    float4 v = *(const float4*)(W + (size_t)(k0 + r) * 1024 + n0 + c4);
    st[r][c4 + 0] = v.x; st[r][c4 + 1] = v.y; st[r][c4 + 2] = v.z; st[r][c4 + 3] = v.w;
    __syncthreads();
    bf16_t tmp[4] __attribute__((aligned(8)));
    #pragma unroll
    for (int i = 0; i < 4; ++i) tmp[i] = (bf16_t)st[c4 + i][r];
    *(uint2*)(o + (size_t)(n0 + r) * 1024 + k0 + c4) = *(const uint2*)tmp;
}

// ---------- MFMA GEMM: C = A[M,1024] @ Bt[N,1024]^T + bias ----------
// r14 form: 128x128 (FUSED) / 64x128 tile, BK=64 slab-pair, XCD-chunked
// swizzle, head-major FUSED epilogue.
template<bool FUSED, int MT>
__global__ __launch_bounds__(256, 3) void gemm_glds(
    const bf16_t* __restrict__ A, const bf16_t* __restrict__ Bt,
    const float* __restrict__ b0, const float* __restrict__ b1,
    const float* __restrict__ b2,
    bf16_t* __restrict__ Qo, bf16_t* __restrict__ Ko, bf16_t* __restrict__ Vo,
    float* __restrict__ Fo)
{
    const int K = 1024;
    __shared__ __align__(16) bf16_t As[2 * MT * 32];
    __shared__ __align__(16) bf16_t Bs[2 * 128 * 32];

    constexpr int NTPW = (MT == 128) ? 4 : 2;
    constexpr int JA   = MT / 64;
    constexpr int NX   = FUSED ? 24 : 8;            // grid.x
    constexpr int NWG  = NX * ((MT == 128) ? 32 : 64);

    const int tid  = threadIdx.x;
    const int wave = tid >> 6;
    const int lane = tid & 63;
    const int quad = lane >> 4;
    const int l16  = lane & 15;

    int flat = blockIdx.y * NX + blockIdx.x;
    flat = (flat & 7) * (NWG >> 3) + (flat >> 3);
    const int m0 = (flat / NX) * MT;
    const int n0 = (flat % NX) * 128;

    const int wm = (MT == 128) ? (wave >> 1) * 64 : 0;
    const int wn = (MT == 128) ? (wave & 1) * 64 : wave * 32;

    int goffA[JA], goffB[2];
    #pragma unroll
    for (int j = 0; j < JA; ++j) {
        const int row = j * 64 + (tid >> 2);
        const int cl  = (tid & 3) ^ ((row >> 1) & 3);
        goffA[j] = (m0 + row) * K + cl * 8;
    }
    #pragma unroll
    for (int j = 0; j < 2; ++j) {
        const int row = j * 64 + (tid >> 2);
        const int cl  = (tid & 3) ^ ((row >> 1) & 3);
        goffB[j] = (n0 + row) * K + cl * 8;
    }
    const int ldsoff = wave * 1024;

    f32x4 acc[4][NTPW] = {};
    const int sw = (l16 >> 1) & 3;

    for (int k0 = 0; k0 < K; k0 += 64) {
        #pragma unroll
        for (int s = 0; s < 2; ++s) {
            #pragma unroll
            for (int j = 0; j < JA; ++j)
                async16(A + goffA[j] + k0 + s * 32,
                        (char*)As + s * (MT * 64) + j * 4096 + ldsoff);
            #pragma unroll
            for (int j = 0; j < 2; ++j)
                async16(Bt + goffB[j] + k0 + s * 32,
                        (char*)Bs + s * 8192 + j * 4096 + ldsoff);
        }
        __syncthreads();

        #pragma unroll
        for (int s = 0; s < 2; ++s) {
            bf16x8 af[4], bfr[NTPW];
            #pragma unroll
            for (int mt = 0; mt < 4; ++mt)
                af[mt] = *(const bf16x8*)(&As[s * (MT * 32) +
                    (wm + mt * 16 + l16) * 32 + (quad ^ sw) * 8]);
            #pragma unroll
            for (int nt = 0; nt < NTPW; ++nt)
                bfr[nt] = *(const bf16x8*)(&Bs[s * (128 * 32) +
                    (wn + nt * 16 + l16) * 32 + (quad ^ sw) * 8]);
            #pragma unroll
            for (int mt = 0; mt < 4; ++mt)
                #pragma unroll
                for (int nt = 0; nt < NTPW; ++nt)
                    acc[mt][nt] = __builtin_amdgcn_mfma_f32_16x16x32_bf16(
                        af[mt], bfr[nt], acc[mt][nt], 0, 0, 0);
        }
        __syncthreads();
    }

    if (FUSED) {
        const int sel = n0 >> 10;
        const float* bias = (sel == 0) ? b0 : (sel == 1) ? b1 : b2;
        bf16_t* Cout      = (sel == 0) ? Qo : (sel == 1) ? Ko : Vo;
        const float scl   = (sel == 1) ? SCALE_LOG2E : 1.0f;
        const int nb = n0 & 1023;
        #pragma unroll
        for (int nt = 0; nt < NTPW; ++nt) {
            const int n = nb + wn + nt * 16 + l16;
            const float bb = bias[n];
            const size_t hbase = (size_t)(n >> 4) * 65536 + (n & 15);
            #pragma unroll
            for (int mt = 0; mt < 4; ++mt)
                #pragma unroll
                for (int i = 0; i < 4; ++i) {
                    const int m = m0 + wm + mt * 16 + quad * 4 + i;
                    Cout[hbase + (size_t)m * 16] = (bf16_t)((acc[mt][nt][i] + bb) * scl);
                }
        }
    } else {
        #pragma unroll
        for (int nt = 0; nt < NTPW; ++nt) {
            const int n = n0 + wn + nt * 16 + l16;
            const float bb = b0[n];
            #pragma unroll
            for (int mt = 0; mt < 4; ++mt)
                #pragma unroll
                for (int i = 0; i < 4; ++i) {
                    const int m = m0 + wm + mt * 16 + quad * 4 + i;
                    Fo[(size_t)m * 1024 + n] = acc[mt][nt][i] + bb;
                }
        }
    }
}

// ---------- MFMA flash attention, key-split 8-wave, head-major inputs ----------
// UNCHANGED from r14 (52.8us). PARKED: 6 structural levers each moved <=2us;
// latency-bound with issue slack (r11 pack-width null).
__global__ __launch_bounds__(512, 4) void attn_kernel(
    const bf16_t* __restrict__ Q, const bf16_t* __restrict__ K,
    const bf16_t* __restrict__ V, bf16_t* __restrict__ Z)
{
    __shared__ __align__(16) char smem[16 * 1032 * 2];
    bf16_t (*Vt)[1032] = (bf16_t (*)[1032])smem;
    float* cmb = (float*)smem;     // [4 waves][64 lanes][21]

    const int tid  = threadIdx.x;
    const int wave = tid >> 6;        // 0..7
    const int lane = tid & 63;
    const int quad = lane >> 4;
    const int l16  = lane & 15;
    const int hd = blockIdx.x >> 2;
    const int qc = blockIdx.x & 3;
    const int a = hd >> 2, b = hd & 3;
    const int qw   = wave & 3;
    const int kvh  = wave >> 2;
    const int qbase = qc * 256 + qw * 64;
    const int kb512 = kvh * 512;

    const size_t hb = (size_t)a * 65536 + (size_t)b * 1024 * 16;

    const int r  = tid >> 2;
    const int dq = (tid & 3) * 4;
    const bf16_t* Vp = V + hb + (size_t)r * 16 + dq;
    #pragma unroll 2
    for (int t = 0; t < 8; ++t) {
        uint2 vv = *(const uint2*)(Vp + t * 2048);   // +128 rows
        bf16_t t4[4] __attribute__((aligned(8)));
        *(uint2*)t4 = vv;
        #pragma unroll
        for (int ii = 0; ii < 4; ++ii)
            Vt[dq + ii][t * 128 + r] = t4[ii];
    }

    bf16x8 qf[4] = {};
    if (quad < 2) {
        #pragma unroll
        for (int qs = 0; qs < 4; ++qs)
            qf[qs] = *(const bf16x8*)(Q + hb +
                (size_t)(qbase + qs * 16 + l16) * 16 + quad * 8);
    }

    const bf16_t* Kp = K + hb + (size_t)(kb512 + l16) * 16 + quad * 8;
    bf16x8 kfA[4] = {}, kfB[4] = {};
    if (quad < 2) {
        #pragma unroll
        for (int kt = 0; kt < 4; ++kt)
            kfA[kt] = *(const bf16x8*)(Kp + kt * 256);   // +16 rows
    }

    __syncthreads();   // Vt ready

    const s16x4 ones = { 0x3F80, 0x3F80, 0x3F80, 0x3F80 };  // bf16 1.0 x4

    f32x4 zacc[4] = {};
    f32x4 lacc[4] = {};

#define ATTN_TILE(JIDX, KFCUR, KFNXT, DO_PREFETCH)                            \
    {                                                                         \
        const int j_ = (JIDX);                                                \
        if (DO_PREFETCH && quad < 2) {                                        \
            _Pragma("unroll")                                                 \
            for (int kt = 0; kt < 4; ++kt)                                    \
                KFNXT[kt] = *(const bf16x8*)(                                 \
                    Kp + (j_ + 1) * 1024 + kt * 256);                         \
        }                                                                     \
        _Pragma("unroll")                                                     \
        for (int kt = 0; kt < 4; ++kt) {                                      \
            const s16x4 vfrag = __builtin_bit_cast(s16x4,                     \
                *(const uint2*)(&Vt[l16][kb512 + j_ * 64 + kt * 16 + quad * 4])); \
            _Pragma("unroll")                                                 \
            for (int qs = 0; qs < 4; ++qs) {                                  \
                f32x4 zc = {0.f, 0.f, 0.f, 0.f};                              \
                f32x4 s = __builtin_amdgcn_mfma_f32_16x16x32_bf16(            \
                    KFCUR[kt], qf[qs], zc, 0, 0, 0);                          \
                const float e0 = __builtin_amdgcn_exp2f(s[0]);                \
                const float e1 = __builtin_amdgcn_exp2f(s[1]);                \
                const float e2 = __builtin_amdgcn_exp2f(s[2]);                \
                const float e3 = __builtin_amdgcn_exp2f(s[3]);                \
                bf16x4 pv;                                                    \
                pv[0] = (bf16_t)e0; pv[1] = (bf16_t)e1;                       \
                pv[2] = (bf16_t)e2; pv[3] = (bf16_t)e3;                       \
                const s16x4 pfrag = __builtin_bit_cast(s16x4, pv);            \
                zacc[qs] = __builtin_amdgcn_mfma_f32_16x16x16bf16_1k(         \
                    vfrag, pfrag, zacc[qs], 0, 0, 0);                         \
                lacc[qs] = __builtin_amdgcn_mfma_f32_16x16x16bf16_1k(         \
                    ones, pfrag, lacc[qs], 0, 0, 0);                          \
            }                                                                 \
        }                                                                     \
    }

    #pragma unroll 1
    for (int j2 = 0; j2 < 4; ++j2) {
        ATTN_TILE(2 * j2,     kfA, kfB, true)
        ATTN_TILE(2 * j2 + 1, kfB, kfA, (j2 < 3))
    }
#undef ATTN_TILE

    __syncthreads();
    if (wave >= 4) {
        float* p = cmb + ((size_t)((wave - 4) * 64 + lane)) * 21;
        #pragma unroll
        for (int qs = 0; qs < 4; ++qs) {
            #pragma unroll
            for (int i = 0; i < 4; ++i) p[qs * 4 + i] = zacc[qs][i];
            p[16 + qs] = lacc[qs][0];
        }
    }
    __syncthreads();
    if (wave < 4) {
        const float* p = cmb + ((size_t)(wave * 64 + lane)) * 21;
        #pragma unroll
        for (int qs = 0; qs < 4; ++qs) {
            const float inv = 1.0f / (lacc[qs][0] + p[16 + qs]);
            const int q = qbase + qs * 16 + l16;
            bf16_t o4[4] __attribute__((aligned(8)));
            #pragma unroll
            for (int i = 0; i < 4; ++i)
                o4[i] = (bf16_t)((zacc[qs][i] + p[qs * 4 + i]) * inv);
            *(uint2*)(Z + ((size_t)hd * 1024 + q) * 16 + quad * 4) = *(const uint2*)o4;
        }
    }
}

extern "C" void kernel_launch(void* const* d_in, const int* in_sizes, int n_in,
                              void* d_out, int out_size, void* d_ws, size_t ws_size,
                              hipStream_t stream) {
    const float* x  = (const float*)d_in[0];
    const float* Wq = (const float*)d_in[1];
    const float* bq = (const float*)d_in[2];
    const float* Wk = (const float*)d_in[3];
    const float* bk = (const float*)d_in[4];
    const float* Wv = (const float*)d_in[5];
    const float* bv = (const float*)d_in[6];
    const float* Wo = (const float*)d_in[7];
    const float* bo = (const float*)d_in[8];
    float* out = (float*)d_out;

    char* ws = (char*)d_ws;
    bf16_t* x_bf = (bf16_t*)(ws);
    bf16_t* Wt   = (bf16_t*)(ws + (8u << 20));   // q|k|v|o slabs, contiguous
    bf16_t* Qb   = (bf16_t*)(ws + (16u << 20));
    bf16_t* Kb   = (bf16_t*)(ws + (24u << 20));
    bf16_t* Vb   = (bf16_t*)(ws + (32u << 20));
    bf16_t* Zb   = (bf16_t*)(ws + (40u << 20));
    bf16_t* WtO  = Wt + (size_t)3 * 1024 * 1024;

    // merged prologue: z<4 transpose W[z], z==4 cast x
    prologue<<<dim3(32, 32, 5), dim3(256), 0, stream>>>(
        x, Wq, Wk, Wv, Wo, x_bf, Wt);

    // fused QKV: Bt = [3072][1024] (Wq|Wk|Wv); Q/K/V written head-major
    gemm_glds<true, 128><<<dim3(24, 32), dim3(256), 0, stream>>>(
        x_bf, Wt, bq, bk, bv, Qb, Kb, Vb, nullptr);

    attn_kernel<<<dim3(1024), dim3(512), 0, stream>>>(Qb, Kb, Vb, Zb);

    // O-projection: r14 form — 64x128 tiles, 512 blocks x 256 thr
    gemm_glds<false, 64><<<dim3(8, 64), dim3(256), 0, stream>>>(
        Zb, WtO, bo, nullptr, nullptr, nullptr, nullptr, nullptr, out);
}

// Round 18
// 181.908 us; speedup vs baseline: 1.0471x; 1.0155x over previous
//
#include <hip/hip_runtime.h>
#include <hip/hip_bf16.h>

// B=4, T=1024, E=1024, ATT=64, NH=16, AH=1024. M = B*T = 4096, K = N = 1024.
// Pipeline: cast x->bf16; transpose+cast W{q,k,v,o} -> [N][K] bf16;
//           fused QKV MFMA GEMM (128x128, BK=64 slab-pair, global_load_lds,
//           XCD-chunked swizzle, HEAD-MAJOR Q/K/V epilogue, K pre-scaled by
//           0.125*log2e); register-path MFMA flash attention (S^T trick,
//           HW v_exp_f32, key-split 8-wave); O-proj GEMM 64x64 (4 blocks/CU).
//
// ROUND 18: (1) REVERT r17 prologue merge (non-attn time +5.8us on a fast
// node — merge was neutral-to-negative; back to r14's two kernels).
// (2) ONE CHANGE: O-proj tile 64x128 -> 64x64, grid 512 -> 1024 blocks =
// 4 blocks/CU = 16 waves/CU of INDEPENDENT 4-wave blocks. r15's occupancy
// theory was never falsified: r16's split-K test coupled 8 waves per
// barrier + combine overhead (different mechanism). This is the clean TLP
// test (m114 implicit overlap: one block computes while another drains).
// Staging algebra verbatim from the proven 64-row pattern; no new sync.
// LEDGER: r10 inline-asm cvt_pk after v_exp => NaN — never hand-write.
// r12 explicit GEMM dbuf +9us. r13 XCD swizzle null (kept). r14 head-major
// QKV -6us (best: 180.7). r15/16 split-K O-proj reverted. r17 prologue
// merge reverted.

typedef __bf16 bf16_t;
typedef bf16_t bf16x8 __attribute__((ext_vector_type(8)));
typedef bf16_t bf16x4 __attribute__((ext_vector_type(4)));
typedef short  s16x4 __attribute__((ext_vector_type(4)));
typedef float  f32x4 __attribute__((ext_vector_type(4)));

#define SCALE_LOG2E 0.18033688011112042f  /* 0.125 * log2(e) */

__device__ __forceinline__ void async16(const bf16_t* g, void* l) {
    __builtin_amdgcn_global_load_lds(
        (const __attribute__((address_space(1))) unsigned int*)g,
        (__attribute__((address_space(3))) unsigned int*)l,
        16, 0, 0);
}

// ---------- cast fp32 -> bf16, 8 elems/thread ----------
__global__ __launch_bounds__(256) void cast_f32_bf16(
    const float* __restrict__ in, bf16_t* __restrict__ out, int n8)
{
    int i = blockIdx.x * 256 + threadIdx.x;
    if (i >= n8) return;
    const float4* p = (const float4*)in + (size_t)i * 2;
    float4 a = p[0], b = p[1];
    bf16x8 o;
    o[0] = (bf16_t)a.x; o[1] = (bf16_t)a.y; o[2] = (bf16_t)a.z; o[3] = (bf16_t)a.w;
    o[4] = (bf16_t)b.x; o[5] = (bf16_t)b.y; o[6] = (bf16_t)b.z; o[7] = (bf16_t)b.w;
    *((bf16x8*)out + i) = o;
}

// ---------- transpose + cast: W [1024][1024] fp32 [K][N] -> [N][K] bf16 ----------
__global__ __launch_bounds__(256) void transpose_cast(
    const float* __restrict__ W0, const float* __restrict__ W1,
    const float* __restrict__ W2, const float* __restrict__ W3,
    bf16_t* __restrict__ out)
{
    __shared__ float st[32][33];
    const float* W = (blockIdx.z == 0) ? W0 : (blockIdx.z == 1) ? W1
                   : (blockIdx.z == 2) ? W2 : W3;
    bf16_t* o = out + (size_t)blockIdx.z * 1024 * 1024;
    const int n0 = blockIdx.x * 32, k0 = blockIdx.y * 32;
    const int t = threadIdx.x;
    const int r = t >> 3, c4 = (t & 7) * 4;
    float4 v = *(const float4*)(W + (size_t)(k0 + r) * 1024 + n0 + c4);
    st[r][c4 + 0] = v.x; st[r][c4 + 1] = v.y; st[r][c4 + 2] = v.z; st[r][c4 + 3] = v.w;
    __syncthreads();
    bf16_t tmp[4] __attribute__((aligned(8)));
    #pragma unroll
    for (int i = 0; i < 4; ++i) tmp[i] = (bf16_t)st[c4 + i][r];
    *(uint2*)(o + (size_t)(n0 + r) * 1024 + k0 + c4) = *(const uint2*)tmp;
}

// ---------- fused QKV MFMA GEMM (UNCHANGED from r14) ----------
// 128x128 tile, BK=64 slab-pair, XCD-chunked swizzle, head-major epilogue.
template<bool FUSED, int MT>
__global__ __launch_bounds__(256, 3) void gemm_glds(
    const bf16_t* __restrict__ A, const bf16_t* __restrict__ Bt,
    const float* __restrict__ b0, const float* __restrict__ b1,
    const float* __restrict__ b2,
    bf16_t* __restrict__ Qo, bf16_t* __restrict__ Ko, bf16_t* __restrict__ Vo,
    float* __restrict__ Fo)
{
    const int K = 1024;
    __shared__ __align__(16) bf16_t As[2 * MT * 32];
    __shared__ __align__(16) bf16_t Bs[2 * 128 * 32];

    constexpr int NTPW = (MT == 128) ? 4 : 2;
    constexpr int JA   = MT / 64;
    constexpr int NX   = FUSED ? 24 : 8;            // grid.x
    constexpr int NWG  = NX * ((MT == 128) ? 32 : 64);

    const int tid  = threadIdx.x;
    const int wave = tid >> 6;
    const int lane = tid & 63;
    const int quad = lane >> 4;
    const int l16  = lane & 15;

    int flat = blockIdx.y * NX + blockIdx.x;
    flat = (flat & 7) * (NWG >> 3) + (flat >> 3);
    const int m0 = (flat / NX) * MT;
    const int n0 = (flat % NX) * 128;

    const int wm = (MT == 128) ? (wave >> 1) * 64 : 0;
    const int wn = (MT == 128) ? (wave & 1) * 64 : wave * 32;

    int goffA[JA], goffB[2];
    #pragma unroll
    for (int j = 0; j < JA; ++j) {
        const int row = j * 64 + (tid >> 2);
        const int cl  = (tid & 3) ^ ((row >> 1) & 3);
        goffA[j] = (m0 + row) * K + cl * 8;
    }
    #pragma unroll
    for (int j = 0; j < 2; ++j) {
        const int row = j * 64 + (tid >> 2);
        const int cl  = (tid & 3) ^ ((row >> 1) & 3);
        goffB[j] = (n0 + row) * K + cl * 8;
    }
    const int ldsoff = wave * 1024;

    f32x4 acc[4][NTPW] = {};
    const int sw = (l16 >> 1) & 3;

    for (int k0 = 0; k0 < K; k0 += 64) {
        #pragma unroll
        for (int s = 0; s < 2; ++s) {
            #pragma unroll
            for (int j = 0; j < JA; ++j)
                async16(A + goffA[j] + k0 + s * 32,
                        (char*)As + s * (MT * 64) + j * 4096 + ldsoff);
            #pragma unroll
            for (int j = 0; j < 2; ++j)
                async16(Bt + goffB[j] + k0 + s * 32,
                        (char*)Bs + s * 8192 + j * 4096 + ldsoff);
        }
        __syncthreads();

        #pragma unroll
        for (int s = 0; s < 2; ++s) {
            bf16x8 af[4], bfr[NTPW];
            #pragma unroll
            for (int mt = 0; mt < 4; ++mt)
                af[mt] = *(const bf16x8*)(&As[s * (MT * 32) +
                    (wm + mt * 16 + l16) * 32 + (quad ^ sw) * 8]);
            #pragma unroll
            for (int nt = 0; nt < NTPW; ++nt)
                bfr[nt] = *(const bf16x8*)(&Bs[s * (128 * 32) +
                    (wn + nt * 16 + l16) * 32 + (quad ^ sw) * 8]);
            #pragma unroll
            for (int mt = 0; mt < 4; ++mt)
                #pragma unroll
                for (int nt = 0; nt < NTPW; ++nt)
                    acc[mt][nt] = __builtin_amdgcn_mfma_f32_16x16x32_bf16(
                        af[mt], bfr[nt], acc[mt][nt], 0, 0, 0);
        }
        __syncthreads();
    }

    if (FUSED) {
        const int sel = n0 >> 10;
        const float* bias = (sel == 0) ? b0 : (sel == 1) ? b1 : b2;
        bf16_t* Cout      = (sel == 0) ? Qo : (sel == 1) ? Ko : Vo;
        const float scl   = (sel == 1) ? SCALE_LOG2E : 1.0f;
        const int nb = n0 & 1023;
        #pragma unroll
        for (int nt = 0; nt < NTPW; ++nt) {
            const int n = nb + wn + nt * 16 + l16;
            const float bb = bias[n];
            const size_t hbase = (size_t)(n >> 4) * 65536 + (n & 15);
            #pragma unroll
            for (int mt = 0; mt < 4; ++mt)
                #pragma unroll
                for (int i = 0; i < 4; ++i) {
                    const int m = m0 + wm + mt * 16 + quad * 4 + i;
                    Cout[hbase + (size_t)m * 16] = (bf16_t)((acc[mt][nt][i] + bb) * scl);
                }
        }
    } else {
        #pragma unroll
        for (int nt = 0; nt < NTPW; ++nt) {
            const int n = n0 + wn + nt * 16 + l16;
            const float bb = b0[n];
            #pragma unroll
            for (int mt = 0; mt < 4; ++mt)
                #pragma unroll
                for (int i = 0; i < 4; ++i) {
                    const int m = m0 + wm + mt * 16 + quad * 4 + i;
                    Fo[(size_t)m * 1024 + n] = acc[mt][nt][i] + bb;
                }
        }
    }
}

// ---------- O-proj GEMM, 64x64 tiles: out = Z[4096,1024] @ WtO^T + bo ----------
// ROUND 18: grid (16,64) = 1024 blocks x 256 thr -> 4 blocks/CU = 16
// waves/CU of independent 4-wave blocks (was 2 blocks/CU at 64x128).
// 4 waves arranged 2Mx2N, each 32x32 output (acc[2][2]). LDS 16KB.
// Staging: one async16/thread/slab for A and B (64-row panels, proven
// XOR-swizzle algebra verbatim).
__global__ __launch_bounds__(256, 4) void gemm_oproj(
    const bf16_t* __restrict__ A, const bf16_t* __restrict__ Bt,
    const float* __restrict__ bias, float* __restrict__ Fo)
{
    const int K = 1024;
    __shared__ __align__(16) bf16_t As[2 * 64 * 32];   // 8KB
    __shared__ __align__(16) bf16_t Bs[2 * 64 * 32];   // 8KB

    const int tid  = threadIdx.x;
    const int wave = tid >> 6;
    const int lane = tid & 63;
    const int quad = lane >> 4;
    const int l16  = lane & 15;

    int flat = blockIdx.y * 16 + blockIdx.x;       // grid (16, 64) = 1024
    flat = (flat & 7) * 128 + (flat >> 3);         // XCD chunk (1024 % 8 == 0)
    const int m0 = (flat / 16) * 64;
    const int n0 = (flat % 16) * 64;

    const int wm = (wave >> 1) * 32;
    const int wn = (wave & 1) * 32;

    const int row = tid >> 2;
    const int cl  = (tid & 3) ^ ((row >> 1) & 3);
    const int goffA = (m0 + row) * K + cl * 8;
    const int goffB = (n0 + row) * K + cl * 8;
    const int ldsoff = wave * 1024;

    f32x4 acc[2][2] = {};
    const int sw = (l16 >> 1) & 3;

    for (int k0 = 0; k0 < K; k0 += 64) {
        #pragma unroll
        for (int s = 0; s < 2; ++s) {
            async16(A + goffA + k0 + s * 32, (char*)As + s * 4096 + ldsoff);
            async16(Bt + goffB + k0 + s * 32, (char*)Bs + s * 4096 + ldsoff);
        }
        __syncthreads();

        #pragma unroll
        for (int s = 0; s < 2; ++s) {
            bf16x8 af[2], bfr[2];
            #pragma unroll
            for (int mt = 0; mt < 2; ++mt)
                af[mt] = *(const bf16x8*)(&As[s * 2048 +
                    (wm + mt * 16 + l16) * 32 + (quad ^ sw) * 8]);
            #pragma unroll
            for (int nt = 0; nt < 2; ++nt)
                bfr[nt] = *(const bf16x8*)(&Bs[s * 2048 +
                    (wn + nt * 16 + l16) * 32 + (quad ^ sw) * 8]);
            #pragma unroll
            for (int mt = 0; mt < 2; ++mt)
                #pragma unroll
                for (int nt = 0; nt < 2; ++nt)
                    acc[mt][nt] = __builtin_amdgcn_mfma_f32_16x16x32_bf16(
                        af[mt], bfr[nt], acc[mt][nt], 0, 0, 0);
        }
        __syncthreads();
    }

    #pragma unroll
    for (int nt = 0; nt < 2; ++nt) {
        const int n = n0 + wn + nt * 16 + l16;
        const float bb = bias[n];
        #pragma unroll
        for (int mt = 0; mt < 2; ++mt)
            #pragma unroll
            for (int i = 0; i < 4; ++i) {
                const int m = m0 + wm + mt * 16 + quad * 4 + i;
                Fo[(size_t)m * 1024 + n] = acc[mt][nt][i] + bb;
            }
    }
}

// ---------- MFMA flash attention, key-split 8-wave, head-major inputs ----------
// UNCHANGED from r14 (52.8us). PARKED: 6 structural levers each moved <=2us;
// latency-bound with issue slack (r11 pack-width null).
__global__ __launch_bounds__(512, 4) void attn_kernel(
    const bf16_t* __restrict__ Q, const bf16_t* __restrict__ K,
    const bf16_t* __restrict__ V, bf16_t* __restrict__ Z)
{
    __shared__ __align__(16) char smem[16 * 1032 * 2];
    bf16_t (*Vt)[1032] = (bf16_t (*)[1032])smem;
    float* cmb = (float*)smem;     // [4 waves][64 lanes][21]

    const int tid  = threadIdx.x;
    const int wave = tid >> 6;        // 0..7
    const int lane = tid & 63;
    const int quad = lane >> 4;
    const int l16  = lane & 15;
    const int hd = blockIdx.x >> 2;
    const int qc = blockIdx.x & 3;
    const int a = hd >> 2, b = hd & 3;
    const int qw   = wave & 3;
    const int kvh  = wave >> 2;
    const int qbase = qc * 256 + qw * 64;
    const int kb512 = kvh * 512;

    const size_t hb = (size_t)a * 65536 + (size_t)b * 1024 * 16;

    const int r  = tid >> 2;
    const int dq = (tid & 3) * 4;
    const bf16_t* Vp = V + hb + (size_t)r * 16 + dq;
    #pragma unroll 2
    for (int t = 0; t < 8; ++t) {
        uint2 vv = *(const uint2*)(Vp + t * 2048);   // +128 rows
        bf16_t t4[4] __attribute__((aligned(8)));
        *(uint2*)t4 = vv;
        #pragma unroll
        for (int ii = 0; ii < 4; ++ii)
            Vt[dq + ii][t * 128 + r] = t4[ii];
    }

    bf16x8 qf[4] = {};
    if (quad < 2) {
        #pragma unroll
        for (int qs = 0; qs < 4; ++qs)
            qf[qs] = *(const bf16x8*)(Q + hb +
                (size_t)(qbase + qs * 16 + l16) * 16 + quad * 8);
    }

    const bf16_t* Kp = K + hb + (size_t)(kb512 + l16) * 16 + quad * 8;
    bf16x8 kfA[4] = {}, kfB[4] = {};
    if (quad < 2) {
        #pragma unroll
        for (int kt = 0; kt < 4; ++kt)
            kfA[kt] = *(const bf16x8*)(Kp + kt * 256);   // +16 rows
    }

    __syncthreads();   // Vt ready

    const s16x4 ones = { 0x3F80, 0x3F80, 0x3F80, 0x3F80 };  // bf16 1.0 x4

    f32x4 zacc[4] = {};
    f32x4 lacc[4] = {};

#define ATTN_TILE(JIDX, KFCUR, KFNXT, DO_PREFETCH)                            \
    {                                                                         \
        const int j_ = (JIDX);                                                \
        if (DO_PREFETCH && quad < 2) {                                        \
            _Pragma("unroll")                                                 \
            for (int kt = 0; kt < 4; ++kt)                                    \
                KFNXT[kt] = *(const bf16x8*)(                                 \
                    Kp + (j_ + 1) * 1024 + kt * 256);                         \
        }                                                                     \
        _Pragma("unroll")                                                     \
        for (int kt = 0; kt < 4; ++kt) {                                      \
            const s16x4 vfrag = __builtin_bit_cast(s16x4,                     \
                *(const uint2*)(&Vt[l16][kb512 + j_ * 64 + kt * 16 + quad * 4])); \
            _Pragma("unroll")                                                 \
            for (int qs = 0; qs < 4; ++qs) {                                  \
                f32x4 zc = {0.f, 0.f, 0.f, 0.f};                              \
                f32x4 s = __builtin_amdgcn_mfma_f32_16x16x32_bf16(            \
                    KFCUR[kt], qf[qs], zc, 0, 0, 0);                          \
                const float e0 = __builtin_amdgcn_exp2f(s[0]);                \
                const float e1 = __builtin_amdgcn_exp2f(s[1]);                \
                const float e2 = __builtin_amdgcn_exp2f(s[2]);                \
                const float e3 = __builtin_amdgcn_exp2f(s[3]);                \
                bf16x4 pv;                                                    \
                pv[0] = (bf16_t)e0; pv[1] = (bf16_t)e1;                       \
                pv[2] = (bf16_t)e2; pv[3] = (bf16_t)e3;                       \
                const s16x4 pfrag = __builtin_bit_cast(s16x4, pv);            \
                zacc[qs] = __builtin_amdgcn_mfma_f32_16x16x16bf16_1k(         \
                    vfrag, pfrag, zacc[qs], 0, 0, 0);                         \
                lacc[qs] = __builtin_amdgcn_mfma_f32_16x16x16bf16_1k(         \
                    ones, pfrag, lacc[qs], 0, 0, 0);                          \
            }                                                                 \
        }                                                                     \
    }

    #pragma unroll 1
    for (int j2 = 0; j2 < 4; ++j2) {
        ATTN_TILE(2 * j2,     kfA, kfB, true)
        ATTN_TILE(2 * j2 + 1, kfB, kfA, (j2 < 3))
    }
#undef ATTN_TILE

    __syncthreads();
    if (wave >= 4) {
        float* p = cmb + ((size_t)((wave - 4) * 64 + lane)) * 21;
        #pragma unroll
        for (int qs = 0; qs < 4; ++qs) {
            #pragma unroll
            for (int i = 0; i < 4; ++i) p[qs * 4 + i] = zacc[qs][i];
            p[16 + qs] = lacc[qs][0];
        }
    }
    __syncthreads();
    if (wave < 4) {
        const float* p = cmb + ((size_t)(wave * 64 + lane)) * 21;
        #pragma unroll
        for (int qs = 0; qs < 4; ++qs) {
            const float inv = 1.0f / (lacc[qs][0] + p[16 + qs]);
            const int q = qbase + qs * 16 + l16;
            bf16_t o4[4] __attribute__((aligned(8)));
            #pragma unroll
            for (int i = 0; i < 4; ++i)
                o4[i] = (bf16_t)((zacc[qs][i] + p[qs * 4 + i]) * inv);
            *(uint2*)(Z + ((size_t)hd * 1024 + q) * 16 + quad * 4) = *(const uint2*)o4;
        }
    }
}

extern "C" void kernel_launch(void* const* d_in, const int* in_sizes, int n_in,
                              void* d_out, int out_size, void* d_ws, size_t ws_size,
                              hipStream_t stream) {
    const float* x  = (const float*)d_in[0];
    const float* Wq = (const float*)d_in[1];
    const float* bq = (const float*)d_in[2];
    const float* Wk = (const float*)d_in[3];
    const float* bk = (const float*)d_in[4];
    const float* Wv = (const float*)d_in[5];
    const float* bv = (const float*)d_in[6];
    const float* Wo = (const float*)d_in[7];
    const float* bo = (const float*)d_in[8];
    float* out = (float*)d_out;

    char* ws = (char*)d_ws;
    bf16_t* x_bf = (bf16_t*)(ws);
    bf16_t* Wt   = (bf16_t*)(ws + (8u << 20));   // q|k|v|o slabs, contiguous
    bf16_t* Qb   = (bf16_t*)(ws + (16u << 20));
    bf16_t* Kb   = (bf16_t*)(ws + (24u << 20));
    bf16_t* Vb   = (bf16_t*)(ws + (32u << 20));
    bf16_t* Zb   = (bf16_t*)(ws + (40u << 20));
    bf16_t* WtO  = Wt + (size_t)3 * 1024 * 1024;

    cast_f32_bf16<<<dim3(2048), dim3(256), 0, stream>>>(x, x_bf, 524288);
    transpose_cast<<<dim3(32, 32, 4), dim3(256), 0, stream>>>(Wq, Wk, Wv, Wo, Wt);

    // fused QKV: Bt = [3072][1024] (Wq|Wk|Wv); Q/K/V written head-major
    gemm_glds<true, 128><<<dim3(24, 32), dim3(256), 0, stream>>>(
        x_bf, Wt, bq, bk, bv, Qb, Kb, Vb, nullptr);

    attn_kernel<<<dim3(1024), dim3(512), 0, stream>>>(Qb, Kb, Vb, Zb);

    // O-projection: 64x64 tiles, 1024 blocks (4/CU = 16 waves/CU)
    gemm_oproj<<<dim3(16, 64), dim3(256), 0, stream>>>(Zb, WtO, bo, out);
}